// Round 14
// baseline (2974.728 us; speedup 1.0000x reference)
//
#include <hip/hip_runtime.h>
#include <hip/hip_bf16.h>
#include <stdint.h>

#define NN 8192
#define DD 1024

typedef __attribute__((ext_vector_type(4))) float f32x4;
typedef __attribute__((ext_vector_type(8))) short bf16x8;
using bf16_t = __hip_bfloat16;

__device__ __forceinline__ void gload16(const void* g, void* l) {
  __builtin_amdgcn_global_load_lds(
      (const __attribute__((address_space(1))) void*)g,
      (__attribute__((address_space(3))) void*)l, 16, 0, 0);
}
__device__ __forceinline__ int imin(int a, int b) { return a < b ? a : b; }

// ---------------- batched cast fp32 -> bf16 (all 3 inputs + 3 weights) -------
__global__ __launch_bounds__(256) void cast6_kernel(
    const float* __restrict__ i0, const float* __restrict__ i1,
    const float* __restrict__ i2, const float* __restrict__ w0,
    const float* __restrict__ w1, const float* __restrict__ w2,
    bf16_t* __restrict__ out_x, bf16_t* __restrict__ out_w) {
  const int nd8 = NN * DD / 8;   // 1<<20
  const int dd8 = DD * DD / 8;   // 1<<17
  int i = blockIdx.x * 256 + threadIdx.x;
  const float* src;
  bf16_t* dst;
  if (i < 3 * nd8) {
    const int r = i >> 20, j = i & (nd8 - 1);
    src = (r == 0 ? i0 : r == 1 ? i1 : i2) + (size_t)j * 8;
    dst = out_x + (size_t)i * 8;
  } else {
    const int k = i - 3 * nd8;
    const int r = k >> 17, j = k & (dd8 - 1);
    src = (r == 0 ? w0 : r == 1 ? w1 : w2) + (size_t)j * 8;
    dst = out_w + (size_t)k * 8;
  }
  const float4 a = ((const float4*)src)[0], b = ((const float4*)src)[1];
  __align__(16) bf16_t tmp[8];
  tmp[0] = __float2bfloat16(a.x); tmp[1] = __float2bfloat16(a.y);
  tmp[2] = __float2bfloat16(a.z); tmp[3] = __float2bfloat16(a.w);
  tmp[4] = __float2bfloat16(b.x); tmp[5] = __float2bfloat16(b.y);
  tmp[6] = __float2bfloat16(b.z); tmp[7] = __float2bfloat16(b.w);
  *(uint4*)dst = *(const uint4*)tmp;
}

// ---------------- batched 128^2 projection GEMM (q,k,v via blockIdx.y) -------
__global__ __launch_bounds__(256, 2)
void gemm_proj(const bf16_t* __restrict__ Abase, const bf16_t* __restrict__ Wbase,
               const float* __restrict__ b0, const float* __restrict__ b1,
               const float* __restrict__ b2, bf16_t* __restrict__ C0,
               bf16_t* __restrict__ C1, bf16_t* __restrict__ C2) {
  __shared__ bf16_t As[128 * 32];
  __shared__ bf16_t Bs[128 * 32];
  const int y = blockIdx.y;
  const bf16_t* A = Abase + (size_t)y * NN * DD;
  const bf16_t* B = Wbase + (size_t)y * DD * DD;
  const float* bias = y == 0 ? b0 : y == 1 ? b1 : b2;
  bf16_t* C = y == 0 ? C0 : y == 1 ? C1 : C2;
  const float scale = y == 0 ? 0.03125f : 1.0f;
  const int ldc = y == 2 ? NN : DD;
  const int K = DD, nbx = DD / 128;

  const int t = threadIdx.x;
  const int nwg = gridDim.x;
  const int bid = (blockIdx.x & 7) * (nwg >> 3) + (blockIdx.x >> 3);
  const int bm = bid / nbx, bn = bid % nbx;
  const int lane = t & 63, wave = t >> 6;
  const int wr = wave >> 1, wc = wave & 1;

  const int c0 = t, c1 = t + 256;
  const bf16_t* ag0 = A + (size_t)(bm * 128 + (c0 >> 2)) * K + (c0 & 3) * 8;
  const bf16_t* ag1 = A + (size_t)(bm * 128 + (c1 >> 2)) * K + (c1 & 3) * 8;
  const bf16_t* bg0 = B + (size_t)(bn * 128 + (c0 >> 2)) * K + (c0 & 3) * 8;
  const bf16_t* bg1 = B + (size_t)(bn * 128 + (c1 >> 2)) * K + (c1 & 3) * 8;
  bf16_t* la0 = As + c0 * 8;
  bf16_t* la1 = As + c1 * 8;
  bf16_t* lb0 = Bs + c0 * 8;
  bf16_t* lb1 = Bs + c1 * 8;

  f32x4 acc[4][4] = {};
  const int fr = lane & 15;
  const int ko = (lane >> 4) * 8;

  for (int kt = 0; kt < K; kt += 32) {
    gload16(ag0 + kt, la0);
    gload16(ag1 + kt, la1);
    gload16(bg0 + kt, lb0);
    gload16(bg1 + kt, lb1);
    __syncthreads();
    bf16x8 af[4], bfv[4];
#pragma unroll
    for (int m = 0; m < 4; m++)
      af[m] = *(const bf16x8*)&As[(wr * 64 + m * 16 + fr) * 32 + ko];
#pragma unroll
    for (int n = 0; n < 4; n++)
      bfv[n] = *(const bf16x8*)&Bs[(wc * 64 + n * 16 + fr) * 32 + ko];
#pragma unroll
    for (int m = 0; m < 4; m++)
#pragma unroll
      for (int n = 0; n < 4; n++)
        acc[m][n] = __builtin_amdgcn_mfma_f32_16x16x32_bf16(af[m], bfv[n], acc[m][n], 0, 0, 0);
    __syncthreads();
  }

  const int rb = (lane >> 4) * 4;
#pragma unroll
  for (int m = 0; m < 4; m++) {
#pragma unroll
    for (int n = 0; n < 4; n++) {
      const int col = bn * 128 + wc * 64 + n * 16 + fr;
      const int row0 = bm * 128 + wr * 64 + m * 16 + rb;
      const float bv = bias[col];
      if (y != 2) {
#pragma unroll
        for (int j = 0; j < 4; j++)
          C[(size_t)(row0 + j) * ldc + col] = __float2bfloat16((acc[m][n][j] + bv) * scale);
      } else {  // transposed store: C[col][row]
        __align__(8) bf16_t tmp[4];
#pragma unroll
        for (int j = 0; j < 4; j++)
          tmp[j] = __float2bfloat16(acc[m][n][j] + bv);
        *(ushort4*)&C[(size_t)col * ldc + row0] = *(const ushort4*)tmp;
      }
    }
  }
}

// ---------------- 256^2 NT GEMM, BK=32, 64 KiB LDS -> 2 blocks/CU ------------
// R8's proven 2-barrier tile schedule scaled to BK=32.  LDS per buffer:
// A [256][32] bf16 (16 KiB) + B (16 KiB); dbuf = 64 KiB -> 2 blocks/CU so
// cross-block waves absorb barrier/memory stalls (m114 mechanism).
// Pair-interleaved layout: line l (128 B) holds rows 2l,2l+1; phys chunk
// (2*kchunk + parity) ^ (l&7).  Reads land 2 lanes/slot (free).
// vmcnt ledger: prologue issues 6 (B0,A0,B1), waits vmcnt(2) = buf0 ready.
// Per tile: 4 stage-gloads after mid-barrier; tile-end vmcnt(2) waits the
// 4 oldest = next buffer's A+B.  MODE 3/4 epilogues as R12 (dual-validated).
template<int MODE>
__global__ __launch_bounds__(512, 4)
void gemm256(const bf16_t* __restrict__ A, int lda,
             const bf16_t* __restrict__ B, int ldb,
             void* __restrict__ Cout, int ldc,
             float* __restrict__ aux, int ksplit, int nkt, int nbx, int Mrows) {
  __shared__ char smem_raw[65536];
  const int t = threadIdx.x;
  const int nwg = gridDim.x;
  const int bid = (blockIdx.x & 7) * (nwg >> 3) + (blockIdx.x >> 3);
  const int bm = bid / nbx, bn = bid % nbx;
  const int lane = t & 63, wave = t >> 6;
  const int wr = wave >> 2, wc = wave & 3;   // 2M x 4N waves
  const int fr = lane & 15, hi = lane >> 4;
  const int k0 = blockIdx.y * ksplit;

  // staging source offsets (inverse of the pair-interleaved layout)
  uint32_t offA[2], offB[2];
#pragma unroll
  for (int j = 0; j < 2; j++) {
    const int c = t + j * 512;
    const int l = c >> 3, s = c & 7;
    const int cl = s ^ (l & 7);
    const int row = 2 * l + (cl & 1), kc = cl >> 1;
    offA[j] = (uint32_t)((bm * 256 + row) * lda + k0 + kc * 8);
    offB[j] = (uint32_t)((bn * 256 + row) * ldb + k0 + kc * 8);
  }

  // ds_read bases: lane (fr,hi), frag row = base + fr, k = hi*8..hi*8+7
  const int lA = (wr * 128 + fr) >> 1, pA = fr & 1;
  const int rdA = lA * 128 + (((2 * hi + pA) ^ (lA & 7)) << 4);
  const int lB = (wc * 64 + fr) >> 1, pB = fr & 1;
  const int rdB = 16384 + lB * 128 + (((2 * hi + pB) ^ (lB & 7)) << 4);

  f32x4 acc[8][4] = {};
  bf16x8 af[4], bl[2], bh[2];

#define STA(buf, kt)                                                           \
  gload16(A + offA[0] + (size_t)(kt) * 32, smem_raw + (buf) * 32768 + t * 16); \
  gload16(A + offA[1] + (size_t)(kt) * 32,                                     \
          smem_raw + (buf) * 32768 + 8192 + t * 16);
#define STB(buf, kt)                                                           \
  gload16(B + offB[0] + (size_t)(kt) * 32,                                     \
          smem_raw + (buf) * 32768 + 16384 + t * 16);                          \
  gload16(B + offB[1] + (size_t)(kt) * 32,                                     \
          smem_raw + (buf) * 32768 + 24576 + t * 16);
#define RDA(buf, mf) \
  (*(const bf16x8*)(smem_raw + (buf) * 32768 + rdA + (mf) * 1024))
#define RDB(buf, nf) \
  (*(const bf16x8*)(smem_raw + (buf) * 32768 + rdB + (nf) * 1024))
#define MFMA8(BF, m0, n0)                                                      \
  _Pragma("unroll") for (int m = 0; m < 4; m++)                                \
  _Pragma("unroll") for (int n = 0; n < 2; n++)                                \
    acc[(m0) + m][(n0) + n] = __builtin_amdgcn_mfma_f32_16x16x32_bf16(         \
        af[m], BF[n], acc[(m0) + m][(n0) + n], 0, 0, 0);

  // prologue: buf0 full + buf1.B
  STB(0, 0) STA(0, 0) STB(1, 1)
  asm volatile("s_waitcnt vmcnt(2)" ::: "memory");
  __builtin_amdgcn_s_barrier();

  const int nit = nkt >> 1;
  for (int it = 0; it < nit; ++it) {
    const int T1 = 2 * it + 1;
    const int s2 = imin(2 * it + 2, nkt - 1);
    const int s3 = imin(2 * it + 3, nkt - 1);

#define TILEX(buf, SA, SB)                                                     \
    bl[0] = RDB(buf, 0); bl[1] = RDB(buf, 1);                                  \
    af[0] = RDA(buf, 0); af[1] = RDA(buf, 1);                                  \
    af[2] = RDA(buf, 2); af[3] = RDA(buf, 3);                                  \
    bh[0] = RDB(buf, 2); bh[1] = RDB(buf, 3);                                  \
    __builtin_amdgcn_s_setprio(1);                                             \
    MFMA8(bl, 0, 0)                                                            \
    MFMA8(bh, 0, 2)                                                            \
    __builtin_amdgcn_s_setprio(0);                                             \
    /* all reads of this buf consumed -> safe to restage */                    \
    __builtin_amdgcn_s_barrier();                                              \
    SA SB                                                                      \
    af[0] = RDA(buf, 4); af[1] = RDA(buf, 5);                                  \
    af[2] = RDA(buf, 6); af[3] = RDA(buf, 7);                                  \
    __builtin_amdgcn_s_setprio(1);                                             \
    MFMA8(bh, 4, 2)                                                            \
    MFMA8(bl, 4, 0)                                                            \
    __builtin_amdgcn_s_setprio(0);                                             \
    asm volatile("s_waitcnt vmcnt(2)" ::: "memory");                           \
    __builtin_amdgcn_s_barrier();

    // tile on buf0 (T0); stages: buf1.A(T1), buf0.B(s2)
    TILEX(0, STA(1, T1), STB(0, s2))
    // tile on buf1 (T1); stages: buf0.A(s2), buf1.B(s3)
    TILEX(1, STA(0, s2), STB(1, s3))
#undef TILEX
  }

  asm volatile("s_waitcnt vmcnt(0)" ::: "memory");
  __builtin_amdgcn_s_barrier();

  const int gr0 = bm * 256 + wr * 128 + hi * 4;
  const int gc0 = bn * 256 + wc * 64 + fr;

  if (MODE == 3) {
    float* rsum = (float*)smem_raw;
    if (t < 256) rsum[t] = 0.f;
    __syncthreads();
    bf16_t* C = (bf16_t*)Cout;
#pragma unroll
    for (int mf = 0; mf < 8; mf++) {
#pragma unroll
      for (int j = 0; j < 4; j++) {
        float rs = 0.f;
#pragma unroll
        for (int nf = 0; nf < 4; nf++) {
          float e2 = exp2f(acc[mf][nf][j] * 1.44269504088896f);
          bf16_t pb = __float2bfloat16(e2);
          C[(size_t)(gr0 + mf * 16 + j) * ldc + gc0 + nf * 16] = pb;
          rs += __bfloat162float(pb);
        }
        rs += __shfl_xor(rs, 1); rs += __shfl_xor(rs, 2);
        rs += __shfl_xor(rs, 4); rs += __shfl_xor(rs, 8);
        if (fr == 0) atomicAdd(&rsum[wr * 128 + mf * 16 + hi * 4 + j], rs);
      }
    }
    __syncthreads();
    if (t < 256) aux[(size_t)bn * Mrows + bm * 256 + t] = rsum[t];
  } else {  // MODE 4: scaled atomic accumulate into zeroed out; aux = inv_l
    float* C = (float*)Cout;
#pragma unroll
    for (int mf = 0; mf < 8; mf++)
#pragma unroll
      for (int j = 0; j < 4; j++) {
        const int row = gr0 + mf * 16 + j;
        const float s = aux[row];
#pragma unroll
        for (int nf = 0; nf < 4; nf++)
          atomicAdd(&C[(size_t)row * ldc + gc0 + nf * 16], acc[mf][nf][j] * s);
      }
  }
#undef STA
#undef STB
#undef RDA
#undef RDB
#undef MFMA8
}

// ---------------- rowsum partials -> 1/l ----------------
__global__ __launch_bounds__(256) void rowsum_inv_kernel(
    const float* __restrict__ partial, float* __restrict__ inv_l, int nb) {
  const int r = blockIdx.x * 256 + threadIdx.x;
  float s = 0.f;
  for (int b = 0; b < nb; b++) s += partial[(size_t)b * NN + r];
  inv_l[r] = 1.f / s;
}

// ---------------- zero out (float4) ----------------
__global__ __launch_bounds__(256) void zero_kernel(float4* __restrict__ p) {
  p[(size_t)blockIdx.x * 256 + threadIdx.x] = make_float4(0.f, 0.f, 0.f, 0.f);
}

extern "C" void kernel_launch(void* const* d_in, const int* in_sizes, int n_in,
                              void* d_out, int out_size, void* d_ws, size_t ws_size,
                              hipStream_t stream) {
  const float* queries = (const float*)d_in[0];
  const float* key_in  = (const float*)d_in[1];
  const float* values  = (const float*)d_in[2];
  const float* Wq = (const float*)d_in[3];
  const float* bq = (const float*)d_in[4];
  const float* Wk = (const float*)d_in[5];
  const float* bk = (const float*)d_in[6];
  const float* Wv = (const float*)d_in[7];
  const float* bv = (const float*)d_in[8];
  float* out = (float*)d_out;
  char* ws = (char*)d_ws;

  const size_t MB = 1024 * 1024;
  bf16_t* qb = (bf16_t*)(ws);                 // 16 MiB
  bf16_t* kb = (bf16_t*)(ws + 16 * MB);       // 16 MiB
  bf16_t* vT = (bf16_t*)(ws + 32 * MB);       // [1024][8192], 16 MiB
  bf16_t* P  = (bf16_t*)(ws + 48 * MB);       // [8192][8192] bf16, 128 MiB
  float* partial = (float*)(ws + 176 * MB);   // [32][8192] fp32, 1 MiB
  float* inv_l   = (float*)(ws + 177 * MB);   // 32 KiB
  // projection-phase staging overlaps the P region (dead until QK^T):
  bf16_t* x3 = (bf16_t*)(ws + 48 * MB);       // 3 x 16 MiB bf16 inputs
  bf16_t* w3 = (bf16_t*)(ws + 96 * MB);       // 3 x 2 MiB bf16 weights

  const int nd8 = NN * DD / 8, dd8 = DD * DD / 8;

  // 1) cast all inputs+weights to bf16 (single launch)
  cast6_kernel<<<(3 * nd8 + 3 * dd8) / 256, 256, 0, stream>>>(
      queries, key_in, values, Wq, Wk, Wv, x3, w3);
  // 2) all three projections (single launch, y selects q/k/v)
  gemm_proj<<<dim3((NN / 128) * (DD / 128), 3), 256, 0, stream>>>(
      x3, w3, bq, bk, bv, qb, kb, vT);
  // 3) fused QK^T -> exp -> bf16 P (+ partial row sums)
  gemm256<3><<<dim3((NN / 256) * (NN / 256)), 512, 0, stream>>>(
      qb, DD, kb, DD, P, NN, partial, 0, DD / 32, NN / 256, NN);
  // 4) l[row] -> 1/l ; zero the output accumulator
  rowsum_inv_kernel<<<NN / 256, 256, 0, stream>>>(partial, inv_l, NN / 256);
  zero_kernel<<<NN * DD / 4 / 256, 256, 0, stream>>>((float4*)out);
  // 5) PV split-K=2, scaled atomic accumulate into out
  gemm256<4><<<dim3((NN / 256) * (DD / 256), 2), 512, 0, stream>>>(
      P, NN, vT, NN, out, DD, inv_l, NN / 2, NN / 2 / 32, DD / 256, NN);
}

// Round 15
// 396.658 us; speedup vs baseline: 7.4995x; 7.4995x over previous
//
#include <hip/hip_runtime.h>
#include <hip/hip_bf16.h>
#include <stdint.h>

#define NN 8192
#define DD 1024

typedef __attribute__((ext_vector_type(4))) float f32x4;
typedef __attribute__((ext_vector_type(8))) short bf16x8;
using bf16_t = __hip_bfloat16;

__device__ __forceinline__ void gload16(const void* g, void* l) {
  __builtin_amdgcn_global_load_lds(
      (const __attribute__((address_space(1))) void*)g,
      (__attribute__((address_space(3))) void*)l, 16, 0, 0);
}
__device__ __forceinline__ int imin(int a, int b) { return a < b ? a : b; }

// ---------------- batched cast fp32 -> bf16 (all 3 inputs + 3 weights) -------
__global__ __launch_bounds__(256) void cast6_kernel(
    const float* __restrict__ i0, const float* __restrict__ i1,
    const float* __restrict__ i2, const float* __restrict__ w0,
    const float* __restrict__ w1, const float* __restrict__ w2,
    bf16_t* __restrict__ out_x, bf16_t* __restrict__ out_w) {
  const int nd8 = NN * DD / 8;   // 1<<20
  const int dd8 = DD * DD / 8;   // 1<<17
  int i = blockIdx.x * 256 + threadIdx.x;
  const float* src;
  bf16_t* dst;
  if (i < 3 * nd8) {
    const int r = i >> 20, j = i & (nd8 - 1);
    src = (r == 0 ? i0 : r == 1 ? i1 : i2) + (size_t)j * 8;
    dst = out_x + (size_t)i * 8;
  } else {
    const int k = i - 3 * nd8;
    const int r = k >> 17, j = k & (dd8 - 1);
    src = (r == 0 ? w0 : r == 1 ? w1 : w2) + (size_t)j * 8;
    dst = out_w + (size_t)k * 8;
  }
  const float4 a = ((const float4*)src)[0], b = ((const float4*)src)[1];
  __align__(16) bf16_t tmp[8];
  tmp[0] = __float2bfloat16(a.x); tmp[1] = __float2bfloat16(a.y);
  tmp[2] = __float2bfloat16(a.z); tmp[3] = __float2bfloat16(a.w);
  tmp[4] = __float2bfloat16(b.x); tmp[5] = __float2bfloat16(b.y);
  tmp[6] = __float2bfloat16(b.z); tmp[7] = __float2bfloat16(b.w);
  *(uint4*)dst = *(const uint4*)tmp;
}

// ---------------- batched 128^2 projection GEMM (q,k,v via blockIdx.y) -------
__global__ __launch_bounds__(256, 2)
void gemm_proj(const bf16_t* __restrict__ Abase, const bf16_t* __restrict__ Wbase,
               const float* __restrict__ b0, const float* __restrict__ b1,
               const float* __restrict__ b2, bf16_t* __restrict__ C0,
               bf16_t* __restrict__ C1, bf16_t* __restrict__ C2) {
  __shared__ bf16_t As[128 * 32];
  __shared__ bf16_t Bs[128 * 32];
  const int y = blockIdx.y;
  const bf16_t* A = Abase + (size_t)y * NN * DD;
  const bf16_t* B = Wbase + (size_t)y * DD * DD;
  const float* bias = y == 0 ? b0 : y == 1 ? b1 : b2;
  bf16_t* C = y == 0 ? C0 : y == 1 ? C1 : C2;
  const float scale = y == 0 ? 0.03125f : 1.0f;
  const int ldc = y == 2 ? NN : DD;
  const int K = DD, nbx = DD / 128;

  const int t = threadIdx.x;
  const int nwg = gridDim.x;
  const int bid = (blockIdx.x & 7) * (nwg >> 3) + (blockIdx.x >> 3);
  const int bm = bid / nbx, bn = bid % nbx;
  const int lane = t & 63, wave = t >> 6;
  const int wr = wave >> 1, wc = wave & 1;

  const int c0 = t, c1 = t + 256;
  const bf16_t* ag0 = A + (size_t)(bm * 128 + (c0 >> 2)) * K + (c0 & 3) * 8;
  const bf16_t* ag1 = A + (size_t)(bm * 128 + (c1 >> 2)) * K + (c1 & 3) * 8;
  const bf16_t* bg0 = B + (size_t)(bn * 128 + (c0 >> 2)) * K + (c0 & 3) * 8;
  const bf16_t* bg1 = B + (size_t)(bn * 128 + (c1 >> 2)) * K + (c1 & 3) * 8;
  bf16_t* la0 = As + c0 * 8;
  bf16_t* la1 = As + c1 * 8;
  bf16_t* lb0 = Bs + c0 * 8;
  bf16_t* lb1 = Bs + c1 * 8;

  f32x4 acc[4][4] = {};
  const int fr = lane & 15;
  const int ko = (lane >> 4) * 8;

  for (int kt = 0; kt < K; kt += 32) {
    gload16(ag0 + kt, la0);
    gload16(ag1 + kt, la1);
    gload16(bg0 + kt, lb0);
    gload16(bg1 + kt, lb1);
    __syncthreads();
    bf16x8 af[4], bfv[4];
#pragma unroll
    for (int m = 0; m < 4; m++)
      af[m] = *(const bf16x8*)&As[(wr * 64 + m * 16 + fr) * 32 + ko];
#pragma unroll
    for (int n = 0; n < 4; n++)
      bfv[n] = *(const bf16x8*)&Bs[(wc * 64 + n * 16 + fr) * 32 + ko];
#pragma unroll
    for (int m = 0; m < 4; m++)
#pragma unroll
      for (int n = 0; n < 4; n++)
        acc[m][n] = __builtin_amdgcn_mfma_f32_16x16x32_bf16(af[m], bfv[n], acc[m][n], 0, 0, 0);
    __syncthreads();
  }

  const int rb = (lane >> 4) * 4;
#pragma unroll
  for (int m = 0; m < 4; m++) {
#pragma unroll
    for (int n = 0; n < 4; n++) {
      const int col = bn * 128 + wc * 64 + n * 16 + fr;
      const int row0 = bm * 128 + wr * 64 + m * 16 + rb;
      const float bv = bias[col];
      if (y != 2) {
#pragma unroll
        for (int j = 0; j < 4; j++)
          C[(size_t)(row0 + j) * ldc + col] = __float2bfloat16((acc[m][n][j] + bv) * scale);
      } else {  // transposed store: C[col][row]
        __align__(8) bf16_t tmp[4];
#pragma unroll
        for (int j = 0; j < 4; j++)
          tmp[j] = __float2bfloat16(acc[m][n][j] + bv);
        *(ushort4*)&C[(size_t)col * ldc + row0] = *(const ushort4*)tmp;
      }
    }
  }
}

// ---------------- 256^2 loose-wave NT GEMM (R8/R12 core, proven stable) ------
// MODE 3: bf16 out = exp(acc), partial row sums -> aux[bn*Mrows + row]
// MODE 4: fp32 atomicAdd(out, acc * aux[row]); blockIdx.y selects K-half.
template<int MODE>
__global__ __launch_bounds__(512, 2)
void gemm256(const bf16_t* __restrict__ A, int lda,
             const bf16_t* __restrict__ B, int ldb,
             void* __restrict__ Cout, int ldc,
             float* __restrict__ aux, int ksplit, int nkt, int nbx, int Mrows) {
  __shared__ char smem_raw[131072];
  const int t = threadIdx.x;
  const int nwg = gridDim.x;
  const int bid = (blockIdx.x & 7) * (nwg >> 3) + (blockIdx.x >> 3);
  const int bm = bid / nbx, bn = bid % nbx;
  const int lane = t & 63, wave = t >> 6;
  const int wr = wave >> 2, wc = wave & 3;   // 2M x 4N waves
  const int fr = lane & 15, hi = lane >> 4;
  const int k0 = blockIdx.y * ksplit;

  const int cswz = ((t & 7) ^ ((t >> 3) & 7)) * 8;  // elements
  uint32_t offA[2][2], offB[2][2];
#pragma unroll
  for (int h = 0; h < 2; h++)
#pragma unroll
    for (int l = 0; l < 2; l++) {
      const int r = h * 128 + l * 64 + (t >> 3);
      offA[h][l] = (uint32_t)((bm * 256 + r) * lda + k0 + cswz);
      offB[h][l] = (uint32_t)((bn * 256 + r) * ldb + k0 + cswz);
    }

  const int e = fr & 7;
  const int rowA = (wr * 128 + fr) * 128, rowB = (wc * 64 + fr) * 128;
  const int rdA_k0 = rowA + ((hi ^ e) << 4);
  const int rdA_k1 = rowA + (((hi + 4) ^ e) << 4);
  const int rdB_k0 = rowB + ((hi ^ e) << 4) + 32768;
  const int rdB_k1 = rowB + (((hi + 4) ^ e) << 4) + 32768;

  f32x4 acc[8][4] = {};
  bf16x8 af[4][2], bl[2][2], bh[2][2];

#define STA(buf, h, kt)                                                        \
  gload16(A + offA[h][0] + (size_t)(kt) * 64,                                  \
          smem_raw + (buf) * 65536 + (h) * 16384 + t * 16);                    \
  gload16(A + offA[h][1] + (size_t)(kt) * 64,                                  \
          smem_raw + (buf) * 65536 + (h) * 16384 + 8192 + t * 16);
#define STB(buf, h, kt)                                                        \
  gload16(B + offB[h][0] + (size_t)(kt) * 64,                                  \
          smem_raw + (buf) * 65536 + 32768 + (h) * 16384 + t * 16);            \
  gload16(B + offB[h][1] + (size_t)(kt) * 64,                                  \
          smem_raw + (buf) * 65536 + 32768 + (h) * 16384 + 8192 + t * 16);
#define RDA(buf, mf, ks)                                                       \
  (*(const bf16x8*)(smem_raw + (buf) * 65536 + ((ks) ? rdA_k1 : rdA_k0) +      \
                    (mf) * 2048))
#define RDB(buf, nf, ks)                                                       \
  (*(const bf16x8*)(smem_raw + (buf) * 65536 + ((ks) ? rdB_k1 : rdB_k0) +      \
                    (nf) * 2048))
#define MFMA8(BF, m0, n0)                                                      \
  _Pragma("unroll") for (int m = 0; m < 4; m++)                                \
  _Pragma("unroll") for (int n = 0; n < 2; n++)                                \
  _Pragma("unroll") for (int ks = 0; ks < 2; ks++)                             \
    acc[(m0) + m][(n0) + n] = __builtin_amdgcn_mfma_f32_16x16x32_bf16(         \
        af[m][ks], BF[n][ks], acc[(m0) + m][(n0) + n], 0, 0, 0);

  // prologue: stage tile0 (buf0) fully + B of tile1 (buf1)
  STB(0, 0, 0) STB(0, 1, 0) STA(0, 0, 0) STA(0, 1, 0)
  STB(1, 0, 1) STB(1, 1, 1)
  asm volatile("s_waitcnt vmcnt(4)" ::: "memory");
  __builtin_amdgcn_s_barrier();

  const int nit = nkt >> 1;
  for (int it = 0; it < nit; ++it) {
    const int T1 = 2 * it + 1;
    const int s2 = imin(2 * it + 2, nkt - 1);
    const int s3 = imin(2 * it + 3, nkt - 1);

#define TILEX(buf, S1, S2, S3, S4)                                             \
    bl[0][0] = RDB(buf, 0, 0); bl[0][1] = RDB(buf, 0, 1);                      \
    bl[1][0] = RDB(buf, 1, 0); bl[1][1] = RDB(buf, 1, 1);                      \
    af[0][0] = RDA(buf, 0, 0); af[0][1] = RDA(buf, 0, 1);                      \
    af[1][0] = RDA(buf, 1, 0); af[1][1] = RDA(buf, 1, 1);                      \
    af[2][0] = RDA(buf, 2, 0); af[2][1] = RDA(buf, 2, 1);                      \
    af[3][0] = RDA(buf, 3, 0); af[3][1] = RDA(buf, 3, 1);                      \
    bh[0][0] = RDB(buf, 2, 0); bh[0][1] = RDB(buf, 2, 1);                      \
    bh[1][0] = RDB(buf, 3, 0); bh[1][1] = RDB(buf, 3, 1);                      \
    __builtin_amdgcn_s_setprio(1);                                             \
    MFMA8(bl, 0, 0)                                                            \
    MFMA8(bh, 0, 2)                                                            \
    __builtin_amdgcn_s_setprio(0);                                             \
    __builtin_amdgcn_s_barrier();                                              \
    S1 S2 S3 S4                                                                \
    af[0][0] = RDA(buf, 4, 0); af[0][1] = RDA(buf, 4, 1);                      \
    af[1][0] = RDA(buf, 5, 0); af[1][1] = RDA(buf, 5, 1);                      \
    af[2][0] = RDA(buf, 6, 0); af[2][1] = RDA(buf, 6, 1);                      \
    af[3][0] = RDA(buf, 7, 0); af[3][1] = RDA(buf, 7, 1);                      \
    __builtin_amdgcn_s_setprio(1);                                             \
    MFMA8(bh, 4, 2)                                                            \
    MFMA8(bl, 4, 0)                                                            \
    __builtin_amdgcn_s_setprio(0);                                             \
    asm volatile("s_waitcnt vmcnt(4)" ::: "memory");                           \
    __builtin_amdgcn_s_barrier();

    TILEX(0, STA(1, 0, T1), STA(1, 1, T1), STB(0, 0, s2), STB(0, 1, s2))
    TILEX(1, STA(0, 0, s2), STA(0, 1, s2), STB(1, 0, s3), STB(1, 1, s3))
#undef TILEX
  }

  asm volatile("s_waitcnt vmcnt(0)" ::: "memory");
  __builtin_amdgcn_s_barrier();

  const int gr0 = bm * 256 + wr * 128 + hi * 4;
  const int gc0 = bn * 256 + wc * 64 + fr;

  if (MODE == 3) {
    float* rsum = (float*)smem_raw;
    if (t < 256) rsum[t] = 0.f;
    __syncthreads();
    bf16_t* C = (bf16_t*)Cout;
#pragma unroll
    for (int mf = 0; mf < 8; mf++) {
#pragma unroll
      for (int j = 0; j < 4; j++) {
        float rs = 0.f;
#pragma unroll
        for (int nf = 0; nf < 4; nf++) {
          float e2 = exp2f(acc[mf][nf][j] * 1.44269504088896f);
          bf16_t pb = __float2bfloat16(e2);
          C[(size_t)(gr0 + mf * 16 + j) * ldc + gc0 + nf * 16] = pb;
          rs += __bfloat162float(pb);
        }
        rs += __shfl_xor(rs, 1); rs += __shfl_xor(rs, 2);
        rs += __shfl_xor(rs, 4); rs += __shfl_xor(rs, 8);
        if (fr == 0) atomicAdd(&rsum[wr * 128 + mf * 16 + hi * 4 + j], rs);
      }
    }
    __syncthreads();
    if (t < 256) aux[(size_t)bn * Mrows + bm * 256 + t] = rsum[t];
  } else {  // MODE 4: scaled atomic accumulate into zeroed out; aux = inv_l
    float* C = (float*)Cout;
#pragma unroll
    for (int mf = 0; mf < 8; mf++)
#pragma unroll
      for (int j = 0; j < 4; j++) {
        const int row = gr0 + mf * 16 + j;
        const float s = aux[row];
#pragma unroll
        for (int nf = 0; nf < 4; nf++)
          atomicAdd(&C[(size_t)row * ldc + gc0 + nf * 16], acc[mf][nf][j] * s);
      }
  }
#undef STA
#undef STB
#undef RDA
#undef RDB
#undef MFMA8
}

// ---------------- rowsum->1/l (blocks 0..31) + zero out (all blocks) ---------
// No inter-block dependency: PV (next launch) reads inv_l and out only after
// this kernel retires.  Saves one launch vs separate rowsum + zero.
__global__ __launch_bounds__(256) void rowsum_zero_kernel(
    const float* __restrict__ partial, float* __restrict__ inv_l,
    float4* __restrict__ out, int nb) {
  const int b = blockIdx.x;
  if (b < NN / 256) {
    const int r = b * 256 + threadIdx.x;
    float s = 0.f;
    for (int k = 0; k < nb; k++) s += partial[(size_t)k * NN + r];
    inv_l[r] = 1.f / s;
  }
  out[(size_t)b * 256 + threadIdx.x] = make_float4(0.f, 0.f, 0.f, 0.f);
}

extern "C" void kernel_launch(void* const* d_in, const int* in_sizes, int n_in,
                              void* d_out, int out_size, void* d_ws, size_t ws_size,
                              hipStream_t stream) {
  const float* queries = (const float*)d_in[0];
  const float* key_in  = (const float*)d_in[1];
  const float* values  = (const float*)d_in[2];
  const float* Wq = (const float*)d_in[3];
  const float* bq = (const float*)d_in[4];
  const float* Wk = (const float*)d_in[5];
  const float* bk = (const float*)d_in[6];
  const float* Wv = (const float*)d_in[7];
  const float* bv = (const float*)d_in[8];
  float* out = (float*)d_out;
  char* ws = (char*)d_ws;

  const size_t MB = 1024 * 1024;
  bf16_t* qb = (bf16_t*)(ws);                 // 16 MiB
  bf16_t* kb = (bf16_t*)(ws + 16 * MB);       // 16 MiB
  bf16_t* vT = (bf16_t*)(ws + 32 * MB);       // [1024][8192], 16 MiB
  bf16_t* P  = (bf16_t*)(ws + 48 * MB);       // [8192][8192] bf16, 128 MiB
  float* partial = (float*)(ws + 176 * MB);   // [32][8192] fp32, 1 MiB
  float* inv_l   = (float*)(ws + 177 * MB);   // 32 KiB
  // projection-phase staging overlaps the P region (dead until QK^T):
  bf16_t* x3 = (bf16_t*)(ws + 48 * MB);       // 3 x 16 MiB bf16 inputs
  bf16_t* w3 = (bf16_t*)(ws + 96 * MB);       // 3 x 2 MiB bf16 weights

  const int nd8 = NN * DD / 8, dd8 = DD * DD / 8;

  // 1) cast all inputs+weights to bf16 (single launch)
  cast6_kernel<<<(3 * nd8 + 3 * dd8) / 256, 256, 0, stream>>>(
      queries, key_in, values, Wq, Wk, Wv, x3, w3);
  // 2) all three projections (single launch, y selects q/k/v)
  gemm_proj<<<dim3((NN / 128) * (DD / 128), 3), 256, 0, stream>>>(
      x3, w3, bq, bk, bv, qb, kb, vT);
  // 3) fused QK^T -> exp -> bf16 P (+ partial row sums)
  gemm256<3><<<dim3((NN / 256) * (NN / 256)), 512, 0, stream>>>(
      qb, DD, kb, DD, P, NN, partial, 0, DD / 64, NN / 256, NN);
  // 4) inv_l + zero the output accumulator (single launch)
  rowsum_zero_kernel<<<NN * DD / 4 / 256, 256, 0, stream>>>(
      partial, inv_l, (float4*)out, NN / 256);
  // 5) PV split-K=2, scaled atomic accumulate into out
  gemm256<4><<<dim3((NN / 256) * (DD / 256), 2), 512, 0, stream>>>(
      P, NN, vT, NN, out, DD, inv_l, NN / 2, NN / 2 / 64, DD / 256, NN);
}